// Round 1
// baseline (357.452 us; speedup 1.0000x reference)
//
#include <hip/hip_runtime.h>

// Pad ragged (sum(seqlen), H) fp32 -> (B=8, S=2048, H=4096) fp32, zero tail.
// Pure streaming: 128 MiB read + 256 MiB write => ~64 us floor at 6.3 TB/s.

#define BATCH   8
#define MAXSEQ  2048
#define HIDDEN  4096
#define HV      (HIDDEN / 4)      // 1024 float4 per hidden row (2^10)
#define ROWV    (MAXSEQ * HV)     // float4 per batch slice = 2^21

__global__ __launch_bounds__(256) void pad_kernel(
    const float4* __restrict__ in,
    const int*    __restrict__ seqlen,
    float4*       __restrict__ out,
    long total)
{
    __shared__ int slen[BATCH];
    __shared__ int soff[BATCH];
    if (threadIdx.x == 0) {
        int acc = 0;
        for (int i = 0; i < BATCH; ++i) {
            int l = seqlen[i];
            slen[i] = l;
            soff[i] = acc;
            acc += l;
        }
    }
    __syncthreads();

    long idx    = (long)blockIdx.x * blockDim.x + threadIdx.x;
    long stride = (long)gridDim.x * blockDim.x;
    const float4 zero = make_float4(0.f, 0.f, 0.f, 0.f);

    for (; idx < total; idx += stride) {
        int b   = (int)(idx >> 21);          // / ROWV
        int rem = (int)(idx & (ROWV - 1));
        int s   = rem >> 10;                 // / HV
        int h   = rem & (HV - 1);
        float4 v = zero;
        if (s < slen[b]) {
            v = in[((long)(soff[b] + s) << 10) + h];
        }
        out[idx] = v;
    }
}

extern "C" void kernel_launch(void* const* d_in, const int* in_sizes, int n_in,
                              void* d_out, int out_size, void* d_ws, size_t ws_size,
                              hipStream_t stream)
{
    const float4* in     = (const float4*)d_in[0];
    const int*    seqlen = (const int*)d_in[1];
    float4*       out    = (float4*)d_out;

    long total = (long)out_size / 4;   // float4 count = 16,777,216

    const int threads = 256;
    const int blocks  = 8192;          // grid-stride: 8 float4 per thread
    pad_kernel<<<blocks, threads, 0, stream>>>(in, seqlen, out, total);
}